// Round 6
// baseline (67.586 us; speedup 1.0000x reference)
//
#include <hip/hip_runtime.h>

// Fused tanh-RNN (T=64, I=64, H=100) + tanh + linear (C=40), B=16384.
// TRANSPOSED formulation: D = A*B, A = register-resident weight fragments,
// B = data^T (x / h). W_hh columns pre-permuted by
//   phi(32kb+8g+e) = 32kb + 16*(e>>2) + 4g + (e&3)
// so MFMA D-output regs ARE the next step's B-fragment after per-lane f16 cvt.
//
// Round-6: the r5 LDS-ring reads were compiler-visible (*(float4*)lds_ptr),
// so LLVM's waitcnt pass inserted its own vmcnt(0) drain before them each
// step (manual vmcnt(15) was dead). Fix: read the ring via inline-asm
// ds_read_b128 with the lgkmcnt(0) INSIDE the same asm block -> the only
// vmem wait in the loop is our counted vmcnt(15). (Single-block form avoids
// the split-asm register-copy hazard; consumers data-depend on outputs.)

typedef _Float16 half8 __attribute__((ext_vector_type(8)));
typedef float float4_t __attribute__((ext_vector_type(4)));

#define SLOT_BYTES 5120   // 5 issues x 1024B (4352 used: 16 rows x 272B)
#define GLOAD16(gp, lp)                                                   \
  __builtin_amdgcn_global_load_lds(                                       \
      (const __attribute__((address_space(1))) void*)(gp),                \
      (__attribute__((address_space(3))) void*)(lp), 16, 0, 0)

__device__ __forceinline__ float tanh_fast(float x) {
  float e = __builtin_amdgcn_exp2f(x * 2.8853900817779268f);
  return 1.0f - 2.0f * __builtin_amdgcn_rcpf(e + 1.0f);
}

__global__ __launch_bounds__(256, 1) void rnn_fused(
    const float* __restrict__ x, const float* __restrict__ W_ih,
    const float* __restrict__ W_hh, const float* __restrict__ b_ih,
    const float* __restrict__ b_hh, const float* __restrict__ fc_W,
    const float* __restrict__ fc_b, float* __restrict__ out, int B)
{
  __shared__ char ring[4][4 * SLOT_BYTES];   // [wave][slot]
  const int lane = threadIdx.x & 63;
  const int wave = threadIdx.x >> 6;
  const int g = lane >> 4;   // k-group / D-row group
  const int c = lane & 15;   // batch col (B,D) == weight row (A)
  const int rowbase = (blockIdx.x * 4 + wave) * 16;
  char* ring_w = &ring[wave][0];
  const unsigned int ring_base =
      (unsigned int)(uintptr_t)(__attribute__((address_space(3))) char*)ring_w;

  // ---- A-fragment weights, register-resident.
  half8 wih[2][7];    // W_ih[16nt+c][32kb+8g+e]
  half8 whh[4][7];    // W_hh[16nt+c][phi(32kb+8g+e)]
  float4_t bias[7];   // (b_ih+b_hh)[16nt+4g+v]

  #pragma unroll
  for (int nt = 0; nt < 7; ++nt) {
    int nb = nt * 16 + 4 * g;
    float4_t bi = {0.f, 0.f, 0.f, 0.f};
    if (nb + 3 < 100) {
      float4_t a = *(const float4_t*)(b_ih + nb);
      float4_t b = *(const float4_t*)(b_hh + nb);
      bi = a + b;
    }
    bias[nt] = bi;

    int nrow = nt * 16 + c;
    bool rv = (nrow < 100);
    #pragma unroll
    for (int kb = 0; kb < 2; ++kb) {
      float4_t f0 = {0.f,0.f,0.f,0.f}, f1 = {0.f,0.f,0.f,0.f};
      if (rv) {
        const float* p = W_ih + nrow * 64 + kb * 32 + g * 8;
        f0 = *(const float4_t*)p;
        f1 = *(const float4_t*)(p + 4);
      }
      half8 h;
      #pragma unroll
      for (int j = 0; j < 4; ++j) { h[j] = (_Float16)f0[j]; h[4 + j] = (_Float16)f1[j]; }
      wih[kb][nt] = h;
    }
    #pragma unroll
    for (int kb = 0; kb < 4; ++kb) {
      int clo = kb * 32 + 4 * g;
      int chi = clo + 16;
      float4_t f0 = {0.f,0.f,0.f,0.f}, f1 = {0.f,0.f,0.f,0.f};
      if (rv && clo + 3 < 100) f0 = *(const float4_t*)(W_hh + nrow * 100 + clo);
      if (rv && chi + 3 < 100) f1 = *(const float4_t*)(W_hh + nrow * 100 + chi);
      half8 h;
      #pragma unroll
      for (int j = 0; j < 4; ++j) { h[j] = (_Float16)f0[j]; h[4 + j] = (_Float16)f1[j]; }
      whh[kb][nt] = h;
    }
  }

  // ---- per-lane DMA source pointers: chunk m = j*64+lane ->
  //      row r = m/17, chunk-in-row c17 = m%17 (c17==16 => pad, dummy src).
  //      LDS linear offset m*16 == r*272 + c17*16 (exact match, no scatter).
  const float* gsrc[5];
  #pragma unroll
  for (int j = 0; j < 5; ++j) {
    int m = j * 64 + lane;
    int r = (m * 3856) >> 16;       // m/17 for m<1000
    int c17 = m - r * 17;
    bool valid = (r < 16) & (c17 < 16);
    int row = rowbase + (valid ? r : 0);
    int col = valid ? c17 * 4 : 0;  // float index within the 64-float step block
    gsrc[j] = x + (size_t)row * 4096 + col;
  }

  // ---- prologue: fill slots 0,1,2 (steps 0..2) -> 15 loads outstanding
  #pragma unroll
  for (int s = 0; s < 3; ++s)
    #pragma unroll
    for (int j = 0; j < 5; ++j)
      GLOAD16(gsrc[j] + s * 64, ring_w + s * SLOT_BYTES + j * 1024);

  float4_t acc[7];
  half8 hfrag[4];
  #pragma unroll
  for (int kb = 0; kb < 4; ++kb) hfrag[kb] = (half8)(_Float16)0.0f;  // h_0 = 0

  const unsigned int roff = (unsigned)(c * 272 + g * 32);  // lane offset in slot

  for (int t = 0; t < 64; ++t) {
    // issue slot t+3 (clamped source; constant 5 issues/step)
    int tp = t + 3; if (tp > 63) tp = 63;
    char* lb = ring_w + ((t + 3) & 3) * SLOT_BYTES;
    #pragma unroll
    for (int j = 0; j < 5; ++j)
      GLOAD16(gsrc[j] + tp * 64, lb + j * 1024);

    // slot t complete once only the 15 newer DMAs remain in flight
    asm volatile("s_waitcnt vmcnt(15)" ::: "memory");

    // read x fragment via asm ds_read (invisible to LLVM's waitcnt pass ->
    // no compiler vmcnt(0) drain). Wait inside the block; consumers depend
    // on outputs, so nothing can be hoisted past the lgkmcnt.
    unsigned int a = ring_base + (unsigned)((t & 3) * SLOT_BYTES) + roff;
    float4_t s0, s1, s2, s3;
    asm volatile(
        "ds_read_b128 %0, %4 offset:0\n\t"
        "ds_read_b128 %1, %4 offset:16\n\t"
        "ds_read_b128 %2, %4 offset:128\n\t"
        "ds_read_b128 %3, %4 offset:144\n\t"
        "s_waitcnt lgkmcnt(0)"
        : "=&v"(s0), "=&v"(s1), "=&v"(s2), "=&v"(s3)
        : "v"(a));
    __builtin_amdgcn_sched_barrier(0);

    // recurrence (register-fed)
    #pragma unroll
    for (int nt = 0; nt < 7; ++nt)
      acc[nt] = __builtin_amdgcn_mfma_f32_16x16x32_f16(whh[0][nt], hfrag[0], bias[nt], 0, 0, 0);
    #pragma unroll
    for (int kb = 1; kb < 4; ++kb)
      #pragma unroll
      for (int nt = 0; nt < 7; ++nt)
        acc[nt] = __builtin_amdgcn_mfma_f32_16x16x32_f16(whh[kb][nt], hfrag[kb], acc[nt], 0, 0, 0);

    // input projection
    half8 xb0, xb1;
    #pragma unroll
    for (int j = 0; j < 4; ++j) {
      xb0[j] = (_Float16)s0[j]; xb0[4 + j] = (_Float16)s1[j];
      xb1[j] = (_Float16)s2[j]; xb1[4 + j] = (_Float16)s3[j];
    }
    #pragma unroll
    for (int nt = 0; nt < 7; ++nt) {
      acc[nt] = __builtin_amdgcn_mfma_f32_16x16x32_f16(wih[0][nt], xb0, acc[nt], 0, 0, 0);
      acc[nt] = __builtin_amdgcn_mfma_f32_16x16x32_f16(wih[1][nt], xb1, acc[nt], 0, 0, 0);
    }

    // h_{t+1} = tanh(preact); D regs -> next B-frag via per-lane cvt only
    #pragma unroll
    for (int nt = 0; nt < 7; ++nt)
      #pragma unroll
      for (int v = 0; v < 4; ++v)
        acc[nt][v] = tanh_fast(acc[nt][v]);

    #pragma unroll
    for (int kb = 0; kb < 4; ++kb) {
      half8 h;
      #pragma unroll
      for (int v = 0; v < 4; ++v) {
        h[v] = (_Float16)acc[2 * kb][v];
        h[4 + v] = (kb < 3) ? (_Float16)acc[2 * kb + 1][v] : (_Float16)0.0f;
      }
      hfrag[kb] = h;
    }
  }

  // ---- epilogue: out^T = fc_W * tanh(h_last)^T + fc_b
  #pragma unroll
  for (int nt = 0; nt < 7; ++nt)
    #pragma unroll
    for (int v = 0; v < 4; ++v)
      acc[nt][v] = tanh_fast(acc[nt][v]);
  #pragma unroll
  for (int kb = 0; kb < 4; ++kb) {
    half8 h;
    #pragma unroll
    for (int v = 0; v < 4; ++v) {
      h[v] = (_Float16)acc[2 * kb][v];
      h[4 + v] = (kb < 3) ? (_Float16)acc[2 * kb + 1][v] : (_Float16)0.0f;
    }
    hfrag[kb] = h;
  }

  half8 wfc[4][3];
  float4_t bfc[3];
  #pragma unroll
  for (int nt = 0; nt < 3; ++nt) {
    int nb = nt * 16 + 4 * g;
    float4_t bi = {0.f,0.f,0.f,0.f};
    if (nb + 3 < 40) bi = *(const float4_t*)(fc_b + nb);
    bfc[nt] = bi;

    int nrow = nt * 16 + c;
    bool rv = (nrow < 40);
    #pragma unroll
    for (int kb = 0; kb < 4; ++kb) {
      int clo = kb * 32 + 4 * g;
      int chi = clo + 16;
      float4_t f0 = {0.f,0.f,0.f,0.f}, f1 = {0.f,0.f,0.f,0.f};
      if (rv && clo + 3 < 100) f0 = *(const float4_t*)(fc_W + nrow * 100 + clo);
      if (rv && chi + 3 < 100) f1 = *(const float4_t*)(fc_W + nrow * 100 + chi);
      half8 h;
      #pragma unroll
      for (int j = 0; j < 4; ++j) { h[j] = (_Float16)f0[j]; h[4 + j] = (_Float16)f1[j]; }
      wfc[kb][nt] = h;
    }
  }

  float4_t oacc[3];
  #pragma unroll
  for (int nt = 0; nt < 3; ++nt) oacc[nt] = bfc[nt];
  #pragma unroll
  for (int kb = 0; kb < 4; ++kb)
    #pragma unroll
    for (int nt = 0; nt < 3; ++nt)
      oacc[nt] = __builtin_amdgcn_mfma_f32_16x16x32_f16(wfc[kb][nt], hfrag[kb], oacc[nt], 0, 0, 0);

  // store: lane (g,c) holds out[rowbase+c][n = 16nt+4g+v]
  #pragma unroll
  for (int nt = 0; nt < 3; ++nt)
    #pragma unroll
    for (int v = 0; v < 4; ++v) {
      int n = nt * 16 + 4 * g + v;
      if (n < 40)
        out[(size_t)(rowbase + c) * 40 + n] = oacc[nt][v];
    }
}

extern "C" void kernel_launch(void* const* d_in, const int* in_sizes, int n_in,
                              void* d_out, int out_size, void* d_ws, size_t ws_size,
                              hipStream_t stream) {
  const float* x    = (const float*)d_in[0];
  const float* W_ih = (const float*)d_in[1];
  const float* W_hh = (const float*)d_in[2];
  const float* b_ih = (const float*)d_in[3];
  const float* b_hh = (const float*)d_in[4];
  const float* fc_W = (const float*)d_in[5];
  const float* fc_b = (const float*)d_in[6];
  float* outp = (float*)d_out;

  int B = in_sizes[0] / 4096;      // 16384
  int grid = (B + 63) / 64;        // 64 batch rows per 4-wave block
  rnn_fused<<<grid, 256, 0, stream>>>(x, W_ih, W_hh, b_ih, b_hh, fc_W, fc_b, outp, B);
}